// Round 7
// baseline (314.070 us; speedup 1.0000x reference)
//
#include <hip/hip_runtime.h>
#include <hip/hip_bf16.h>

// MultiScaleFeatureExtractor on MI355X (gfx950) — Round 13
// Math restructuring (unchanged):
//   logits = x @ (Wx@Wslice) + (bx@Wslice + bslice)      (px never materialized)
//   out[s,d] = (sum_n w[n,s]*fx[n,d]) / (sum_n w[n,s] + 0.01)
// R13 vs R12 (counter-driven):
//   - R12: DPP+exp2 neutral -> no pipe saturated (MFMA 20%, VALU 43%, LDS ~35%),
//     kernel is stall-bound at 2 waves/SIMD (register-locked: 124V+128A=252/256).
//   - Un-attacked stall: epilogue cross-XCD atomics. WRITE_SIZE=33.8MB ==
//     full atomic volume (Tg is 256KB; L2-resident atomics would write ~0.3MB)
//     -> every atomicAdd is a cross-XCD RMW round-trip, serializing block
//     retirement 8 generations deep.
//   - R13: per-block partial STORES (fire-and-forget, coalesced, same 33MB
//     but no RMW) into Pg[bh][tslot][64][64] + ngP partials; new final2 kernel
//     reduces 128 tiles (33MB coalesced float4 reads, ~7-12us). Tg memset
//     dispatch removed. Main loop body untouched.
//
// ws layout (NEED = 35,129,344 B):
//   [0,        33554432)  Pg   f32 [bh(16)][tslot(128)][s(64)][d(64)] block partials
//   [33554432, 34603008)  ngP  f32 [bh(16)][tslot(128)][wv(2)][s(64)] norm partials
//   [34603008, 35127296)  WtF  bf16 B-frags [proj(2)][head(8)][nt(4)][ks(8)][lane(64)][j(8)]
//   [35127296, 35129344)  bc   f32 [512]

typedef __attribute__((ext_vector_type(8))) short short8;
typedef __attribute__((ext_vector_type(4))) short short4v;
typedef __attribute__((ext_vector_type(4))) float float4v;
typedef __attribute__((ext_vector_type(2))) unsigned int uint2v;

#define MP 36        // wT/fT pitch: 32-token rows + 4 pad shorts (R4 measured 0 conflicts)
#define XP 264       // XS pitch in shorts: 528B rows (16B multiple; l16-lane frag reads 2-way = free)

// 16-lane rotate-accumulate on the VALU (DPP ROW_ROR:n = ctrl 0x120|n).
// After ror8,ror4,ror2,ror1 accumulation every lane of the row holds the row sum.
#define DPP_ADD(s, ctrl)                                                     \
    s += __int_as_float(__builtin_amdgcn_mov_dpp(__float_as_int(s), ctrl,    \
                                                 0xF, 0xF, true))

__device__ __forceinline__ unsigned short f2bf(float f) {
    union { float f; unsigned int u; } v; v.f = f;
    unsigned int r = (v.u + 0x7FFFu + ((v.u >> 16) & 1u)) >> 16;  // RNE
    return (unsigned short)r;
}

__device__ __forceinline__ unsigned int pack2(float a, float b) {
    __hip_bfloat162 h = __float22bfloat162_rn(float2{a, b});
    union { __hip_bfloat162 h; unsigned int u; } cv; cv.h = h;
    return cv.u;   // low 16 = a, high 16 = b
}

// ---- prep4: fold Wx@Wslice + reformat Wfx into B-frag order; compute bc. (R6, unchanged)
__global__ __launch_bounds__(256)
void msfe_prep4(const float* __restrict__ Wx, const float* __restrict__ bx,
                const float* __restrict__ Wfx,
                const float* __restrict__ Wslice, const float* __restrict__ bslice,
                unsigned short* __restrict__ WtF, float* __restrict__ bcv) {
    const int b = blockIdx.x, t = threadIdx.x;
    if (b < 256) {
        const int head = b >> 5, oct = b & 31;
        __shared__ float Wsl[64 * 65];          // [d][s] +1 pad
        __shared__ float WxS[8 * 64];           // [j][d]
        __shared__ unsigned short stg[8 * 64];  // [j][s]
        #pragma unroll
        for (int i = 0; i < 16; ++i) {          // Wslice: 4096 floats, coalesced
            int idx = i * 256 + t; int d = idx >> 6, s = idx & 63;
            Wsl[d * 65 + s] = Wslice[idx];
        }
        #pragma unroll
        for (int i = 0; i < 2; ++i) {           // 8 Wx rows x 64 ch, coalesced 256B rows
            int idx = i * 256 + t; int j = idx >> 6, d = idx & 63;
            WxS[j * 64 + d] = Wx[(long)(oct * 8 + j) * 512 + head * 64 + d];
        }
        __syncthreads();
        const int s = t & 63;
        #pragma unroll
        for (int rep = 0; rep < 2; ++rep) {
            int j = (t >> 6) + rep * 4;         // wave-uniform j
            float a0 = 0.f, a1 = 0.f, a2 = 0.f, a3 = 0.f;
            #pragma unroll
            for (int d = 0; d < 64; d += 4) {   // WxS broadcast (free), Wsl 2-way (free)
                a0 += WxS[j * 64 + d]     * Wsl[(d)     * 65 + s];
                a1 += WxS[j * 64 + d + 1] * Wsl[(d + 1) * 65 + s];
                a2 += WxS[j * 64 + d + 2] * Wsl[(d + 2) * 65 + s];
                a3 += WxS[j * 64 + d + 3] * Wsl[(d + 3) * 65 + s];
            }
            stg[j * 64 + s] = f2bf((a0 + a1) + (a2 + a3));
        }
        __syncthreads();
        if (t < 64) {
            int nt = t >> 4, l16 = t & 15;
            int ks = oct >> 2, quad = oct & 3;
            int lane = quad * 16 + l16;
            short8 o;
            #pragma unroll
            for (int j = 0; j < 8; ++j) o[j] = (short)stg[j * 64 + nt * 16 + l16];
            *(short8*)(WtF + ((((long)(0 * 8 + head) * 4 + nt) * 8 + ks) * 64 + lane) * 8) = o;
        }
    } else if (b < 320) {
        const int head = (b - 256) >> 3, ks = (b - 256) & 7;
        const int nt = t >> 6, lane = t & 63;
        const int quad = lane >> 4, l16 = lane & 15;
        short8 o;
        #pragma unroll
        for (int j = 0; j < 8; ++j)             // 4x64B segments per instr
            o[j] = (short)f2bf(Wfx[(long)(ks * 32 + quad * 8 + j) * 512 + head * 64 + nt * 16 + l16]);
        *(short8*)(WtF + ((((long)(1 * 8 + head) * 4 + nt) * 8 + ks) * 64 + lane) * 8) = o;
    } else {
        #pragma unroll
        for (int p = 0; p < 2; ++p) {
            int j = t + p * 256;
            int h = j >> 6, s = j & 63;
            float bsum = bslice[s];
            for (int d = 0; d < 64; ++d) bsum += bx[h * 64 + d] * Wslice[d * 64 + s];
            bcv[j] = bsum;
        }
    }
}

// ---- main11: 2048 blocks x 256 thr (4 waves), 512-token tiles, 16 x 32-token chunks.
// Weights pinned in AGPRs ("+a"); x staged fp32->bf16 in-block (R8 staging).
// R13: epilogue = partial STORES (no atomics). Loop body identical to R12.
__global__ __launch_bounds__(256, 2)
void msfe_main11(const float* __restrict__ x,
                 const unsigned short* __restrict__ WtF,
                 const float* __restrict__ bcv,
                 const float* __restrict__ bfx,
                 const float* __restrict__ temperature,
                 float* __restrict__ Pg, float* __restrict__ ngP) {
    __shared__ unsigned short wT[2][64 * MP];              // [s][token] bf16, double-buffered
    __shared__ unsigned short fT[2][64 * MP];              // [d][token]
    __shared__ __align__(16) unsigned short XS[2][32 * XP];// [token][ch] bf16 x-stage, dbuf

    const int tid  = threadIdx.x;
    const int lane = tid & 63;
    const int wv   = tid >> 6;    // 0..3
    const int quad = lane >> 4;
    const int l16  = lane & 15;

    // swizzle: a tile's 8 head-blocks land on one XCD in the same dispatch round
    const int bidx = blockIdx.x;                     // 0..2047
    const int tile = (bidx >> 6) * 8 + (bidx & 7);   // 0..255 (512 tokens each)
    const int head = (bidx >> 3) & 7;
    const int batch = tile >> 7;

    const int proj = wv >> 1;   // waves 0,1: logits+softmax; 2,3: fx
    const int tw   = wv & 1;    // 16-token sub-tile within 32-token chunk

    // ---- weight fragments -> AGPRs, pinned (R6: "+a" leaves VGPRs for loads).
    short8 wfr[4][8];
    {
        const unsigned short* wb = WtF + (((long)(proj * 8 + head) * 4) * 8) * 512 + (long)lane * 8;
        #pragma unroll
        for (int nt = 0; nt < 4; ++nt)
            #pragma unroll
            for (int ks = 0; ks < 8; ++ks)
                wfr[nt][ks] = *(const short8*)(wb + (nt * 8 + ks) * 512);
    }
    #pragma unroll
    for (int nt = 0; nt < 4; ++nt)
        #pragma unroll
        for (int ks = 0; ks < 8; ++ks)
            asm volatile("" : "+a"(wfr[nt][ks]));

    float tmp = temperature[head];
    tmp = fminf(fmaxf(tmp, 0.5f), 5.0f);
    const float invt = 1.0f / tmp;
    const float invt2 = invt * 1.44269504088896f;   // fold log2e: exp(z) = exp2(z*log2e)

    float bias[4];
    #pragma unroll
    for (int nt = 0; nt < 4; ++nt)
        bias[nt] = (proj == 0 ? bcv : bfx)[head * 64 + nt * 16 + l16];
    if (proj == 0) {
        #pragma unroll
        for (int nt = 0; nt < 4; ++nt) bias[nt] *= invt2;  // e = exp2f(fma(acc, invt2, bias))
    }

    float4v Tac[4];
    #pragma unroll
    for (int nt = 0; nt < 4; ++nt) Tac[nt] = (float4v){0.f, 0.f, 0.f, 0.f};
    float normAcc[4] = {0.f, 0.f, 0.f, 0.f};

    // fp32 x base for this tile (512 tokens x 256 ch)
    const float4v* xg4 = (const float4v*)(x + (long)tile * 512 * 256);

    // ---- prologue: stage chunk 0 into XS[0].  (R8 verbatim)
    {
        float4v xs[8];
        #pragma unroll
        for (int i = 0; i < 8; ++i) xs[i] = xg4[i * 256 + tid];
        #pragma unroll
        for (int i = 0; i < 8; ++i) {
            uint2v p;
            p.x = pack2(xs[i].x, xs[i].y);
            p.y = pack2(xs[i].z, xs[i].w);
            *(uint2v*)(&XS[0][(i * 4 + wv) * XP + lane * 4]) = p;
        }
    }
    __syncthreads();

    for (int c = 0; c < 16; ++c) {
        const int wbuf = c & 1, rbuf = wbuf ^ 1;

        // A-frags from the x-stage: token = tw*16+l16, ch = ks*32+quad*8+j.
        short8 afr[8];
        #pragma unroll
        for (int ks = 0; ks < 8; ++ks)
            afr[ks] = *(const short8*)(&XS[wbuf][(tw * 16 + l16) * XP + ks * 32 + quad * 8]);

        // P1: [16 tok x 64 cols] += A(x) * B(w-AGPRs), K=256
        float4v acc[4];
        #pragma unroll
        for (int nt = 0; nt < 4; ++nt) acc[nt] = (float4v){0.f, 0.f, 0.f, 0.f};
        __builtin_amdgcn_s_setprio(1);
        #pragma unroll
        for (int ks = 0; ks < 8; ++ks) {
            #pragma unroll
            for (int nt = 0; nt < 4; ++nt)
                acc[nt] = __builtin_amdgcn_mfma_f32_16x16x32_bf16(afr[ks], wfr[nt][ks], acc[nt], 0, 0, 0);
        }
        __builtin_amdgcn_s_setprio(0);

        // issue next chunk's fp32 loads (afr now dead -> regs reuse)
        float4v xst[8];
        if (c < 15) {
            #pragma unroll
            for (int i = 0; i < 8; ++i)
                xst[i] = xg4[(c + 1) * 2048 + i * 256 + tid];
        }

        // P3 (skewed): T[s][d] += w^T fx over PREVIOUS chunk's 32 tokens.
        if (c > 0) {
            short8 a = *(const short8*)(&wT[rbuf][(wv * 16 + l16) * MP + quad * 8]);
            __builtin_amdgcn_s_setprio(1);
            #pragma unroll
            for (int nt = 0; nt < 4; ++nt) {
                short8 bf = *(const short8*)(&fT[rbuf][(nt * 16 + l16) * MP + quad * 8]);
                Tac[nt] = __builtin_amdgcn_mfma_f32_16x16x32_bf16(a, bf, Tac[nt], 0, 0, 0);
            }
            __builtin_amdgcn_s_setprio(0);
        }

        // P2: softmax / bias -> transposed bf16 into wbuf.
        if (proj == 0) {
            float e[4][4];
            #pragma unroll
            for (int nt = 0; nt < 4; ++nt)
                #pragma unroll
                for (int rr = 0; rr < 4; ++rr)
                    e[nt][rr] = exp2f(fmaf(acc[nt][rr], invt2, bias[nt]));  // log2e prefolded
            #pragma unroll
            for (int rr = 0; rr < 4; ++rr) {
                float s = (e[0][rr] + e[1][rr]) + (e[2][rr] + e[3][rr]);
                DPP_ADD(s, 0x128);   // += ror8
                DPP_ADD(s, 0x124);   // += ror4
                DPP_ADD(s, 0x122);   // += ror2
                DPP_ADD(s, 0x121);   // += ror1
                float inv = __builtin_amdgcn_rcpf(s);   // ~1ulp; threshold 3e-3
                e[0][rr] *= inv; e[1][rr] *= inv; e[2][rr] *= inv; e[3][rr] *= inv;
            }
            #pragma unroll
            for (int nt = 0; nt < 4; ++nt) {
                normAcc[nt] += e[nt][0] + e[nt][1] + e[nt][2] + e[nt][3];
                uint2v p;
                p.x = pack2(e[nt][0], e[nt][1]);
                p.y = pack2(e[nt][2], e[nt][3]);
                *(uint2v*)(&wT[wbuf][(nt * 16 + l16) * MP + tw * 16 + quad * 4]) = p;
            }
        } else {
            #pragma unroll
            for (int nt = 0; nt < 4; ++nt) {
                uint2v p;
                p.x = pack2(acc[nt][0] + bias[nt], acc[nt][1] + bias[nt]);
                p.y = pack2(acc[nt][2] + bias[nt], acc[nt][3] + bias[nt]);
                *(uint2v*)(&fT[wbuf][(nt * 16 + l16) * MP + tw * 16 + quad * 4]) = p;
            }
        }

        // stage next chunk into the buffer this chunk just consumed  (R8 verbatim)
        if (c < 15) {
            #pragma unroll
            for (int i = 0; i < 8; ++i) {
                uint2v p;
                p.x = pack2(xst[i].x, xst[i].y);
                p.y = pack2(xst[i].z, xst[i].w);
                *(uint2v*)(&XS[rbuf][(i * 4 + wv) * XP + lane * 4]) = p;
            }
        }

        __syncthreads();   // single barrier per chunk (covers wT/fT and XS)
    }

    // final P3 on the last written buffer (chunk 15 -> buf 1)
    {
        short8 a = *(const short8*)(&wT[1][(wv * 16 + l16) * MP + quad * 8]);
        #pragma unroll
        for (int nt = 0; nt < 4; ++nt) {
            short8 bf = *(const short8*)(&fT[1][(nt * 16 + l16) * MP + quad * 8]);
            Tac[nt] = __builtin_amdgcn_mfma_f32_16x16x32_bf16(a, bf, Tac[nt], 0, 0, 0);
        }
    }

    // ---- epilogue: per-block partial STORES (fire-and-forget; no cross-XCD RMW).
    // Block owns slice (bh, tslot): bh = batch*8+head, tslot = tile&127. Waves
    // write disjoint s-rows (s = wv*16+quad*4+rr), so no intra-block races.
    const int bh = batch * 8 + head;
    const int tslot = tile & 127;
    float* Pb = Pg + (long)(bh * 128 + tslot) * 4096;
    #pragma unroll
    for (int nt = 0; nt < 4; ++nt) {
        #pragma unroll
        for (int rr = 0; rr < 4; ++rr) {
            int s = wv * 16 + quad * 4 + rr;
            int d = nt * 16 + l16;
            Pb[s * 64 + d] = Tac[nt][rr];
        }
    }
    if (proj == 0) {
        // cross-quad reduce (lanes with equal l16), then quad0 stores 64 values/wave
        #pragma unroll
        for (int nt = 0; nt < 4; ++nt) {
            float v = normAcc[nt];
            v += __shfl_xor(v, 16);
            v += __shfl_xor(v, 32);
            if (quad == 0)
                ngP[((long)(bh * 128 + tslot) * 2 + wv) * 64 + nt * 16 + l16] = v;
        }
    }
}

// ---- final2: reduce 128 tile-partials per (bh) and divide by (ngsum + 0.01).
// grid 256 x 256: block = (bh = blk>>4, sgrp = blk&15 -> 4 s-rows).
__global__ __launch_bounds__(256)
void msfe_final2(const float* __restrict__ Pg, const float* __restrict__ ngP,
                 float* __restrict__ out) {
    __shared__ float redp[4][4];
    __shared__ float ngs[4];
    __shared__ float4v red2[256];

    const int tid = threadIdx.x;
    const int bh = blockIdx.x >> 4;
    const int s0 = (blockIdx.x & 15) * 4;

    // phase 1: ngs[ss] = 0.01 + sum over 256 (tslot,wv) of ngP[bh][tslot][wv][s0+ss]
    {
        const float* gp = ngP + ((long)bh * 256 + tid) * 64 + s0;
        float v0 = gp[0], v1 = gp[1], v2 = gp[2], v3 = gp[3];
        #pragma unroll
        for (int m = 1; m < 64; m <<= 1) {
            v0 += __shfl_xor(v0, m); v1 += __shfl_xor(v1, m);
            v2 += __shfl_xor(v2, m); v3 += __shfl_xor(v3, m);
        }
        if ((tid & 63) == 0) {
            int w = tid >> 6;
            redp[0][w] = v0; redp[1][w] = v1; redp[2][w] = v2; redp[3][w] = v3;
        }
        __syncthreads();
        if (tid < 4)
            ngs[tid] = ((redp[tid][0] + redp[tid][1]) + (redp[tid][2] + redp[tid][3])) + 0.01f;
    }

    // phase 2: sum Pg over 128 tslots, split 4-ways across tq; float4 per thread.
    // tid = tq*64 + ss*16 + d4
    const int d4 = tid & 15;
    const int ss = (tid >> 4) & 3;
    const int tq = tid >> 6;
    const float4v* pp = (const float4v*)Pg;
    const long base = (long)(bh * 128 + tq * 32) * 1024 + (s0 + ss) * 16 + d4;
    float4v a4 = (float4v){0.f, 0.f, 0.f, 0.f};
    #pragma unroll 8
    for (int t = 0; t < 32; ++t) {
        float4v v = pp[base + (long)t * 1024];
        a4.x += v.x; a4.y += v.y; a4.z += v.z; a4.w += v.w;
    }
    red2[tid] = a4;
    __syncthreads();
    if (tid < 64) {
        int ss2 = tid >> 4, dd4 = tid & 15;
        float4v a = red2[0 * 64 + ss2 * 16 + dd4];
        float4v b = red2[1 * 64 + ss2 * 16 + dd4];
        float4v c = red2[2 * 64 + ss2 * 16 + dd4];
        float4v d = red2[3 * 64 + ss2 * 16 + dd4];
        float inv = 1.0f / ngs[ss2];
        float4v o;
        o.x = (a.x + b.x + c.x + d.x) * inv;
        o.y = (a.y + b.y + c.y + d.y) * inv;
        o.z = (a.z + b.z + c.z + d.z) * inv;
        o.w = (a.w + b.w + c.w + d.w) * inv;
        ((float4v*)out)[(long)bh * 1024 + (s0 + ss2) * 16 + dd4] = o;
    }
}

extern "C" void kernel_launch(void* const* d_in, const int* in_sizes, int n_in,
                              void* d_out, int out_size, void* d_ws, size_t ws_size,
                              hipStream_t stream) {
    const float* x       = (const float*)d_in[0];
    const float* Wx      = (const float*)d_in[1];
    const float* bx      = (const float*)d_in[2];
    const float* Wfx     = (const float*)d_in[3];
    const float* bfx     = (const float*)d_in[4];
    const float* Wslice  = (const float*)d_in[5];
    const float* bslice  = (const float*)d_in[6];
    const float* temp    = (const float*)d_in[7];

    char* ws = (char*)d_ws;
    float* Pg  = (float*)ws;                                  // 33,554,432 B
    float* ngP = (float*)(ws + 33554432);                     //  1,048,576 B
    unsigned short* WtF = (unsigned short*)(ws + 34603008);   //    524,288 B
    float* bc  = (float*)(ws + 35127296);                     //      2,048 B

    // no memset needed: every Pg/ngP slot is written unconditionally by main11
    msfe_prep4<<<321, 256, 0, stream>>>(Wx, bx, Wfx, Wslice, bslice, WtF, bc);
    msfe_main11<<<2048, 256, 0, stream>>>(x, WtF, bc, bfx, temp, Pg, ngP);
    msfe_final2<<<256, 256, 0, stream>>>(Pg, ngP, (float*)d_out);
}